// Round 12
// baseline (172.037 us; speedup 1.0000x reference)
//
#include <hip/hip_runtime.h>
#include <hip/hip_bf16.h>

#define LOG2E 1.4426950408889634f
#define LN2   0.6931471805599453f
#define NEG2  (-1.4426950e30f)
#define EXP2F(x) __builtin_exp2f(x)
#define LOG2F(x) __builtin_log2f(x)
#define LDEXPF(x,k) __builtin_ldexpf((x),(k))

// DPP whole-wave shifts. shr: lane i <- lane i-1 (lane0 gets old).
//                        shl: lane i <- lane i+1 (lane63 gets old).
__device__ __forceinline__ float dpp_shr1_f(float x, float old) {
    return __int_as_float(__builtin_amdgcn_update_dpp(
        __float_as_int(old), __float_as_int(x), 0x138, 0xF, 0xF, false));
}
__device__ __forceinline__ int dpp_shr1_i(int x, int old) {
    return __builtin_amdgcn_update_dpp(old, x, 0x138, 0xF, 0xF, false);
}
__device__ __forceinline__ float dpp_shl1_f(float x, float old) {
    return __int_as_float(__builtin_amdgcn_update_dpp(
        __float_as_int(old), __float_as_int(x), 0x130, 0xF, 0xF, false));
}
__device__ __forceinline__ int dpp_shl1_i(int x, int old) {
    return __builtin_amdgcn_update_dpp(old, x, 0x130, 0xF, 0xF, false);
}

__device__ __forceinline__ unsigned bf16r(float x) {
    return (__float_as_uint(x) + 0x8000u) >> 16;
}

__device__ __forceinline__ void async16(void* lds, const void* g) {
    __builtin_amdgcn_global_load_lds(
        (const __attribute__((address_space(1))) unsigned int*)g,
        (__attribute__((address_space(3))) unsigned int*)lds, 16, 0, 0);
}
__device__ __forceinline__ void async4(void* lds, const void* g) {
    __builtin_amdgcn_global_load_lds(
        (const __attribute__((address_space(1))) unsigned int*)g,
        (__attribute__((address_space(3))) unsigned int*)lds, 4, 0, 0);
}

__device__ __forceinline__ void unpack8(const uint4& q, float (&p)[8]) {
    p[0] = __uint_as_float(q.x << 16);
    p[1] = __uint_as_float(q.x & 0xFFFF0000u);
    p[2] = __uint_as_float(q.y << 16);
    p[3] = __uint_as_float(q.y & 0xFFFF0000u);
    p[4] = __uint_as_float(q.z << 16);
    p[5] = __uint_as_float(q.z & 0xFFFF0000u);
    p[6] = __uint_as_float(q.w << 16);
    p[7] = __uint_as_float(q.w & 0xFFFF0000u);
}

// ===========================================================================
// Fused emission-probability precompute: blocks [0,16000) = ph, rest = err.
// PHF32: ph probs stored f32 (row 2048B); else bf16 (row 1024B). err bf16.
// ===========================================================================
template <bool PHF32>
__global__ __launch_bounds__(256) void prob_kernel(
    const float* __restrict__ ph_logits, const int* __restrict__ ph_tgt,
    void* __restrict__ Pph_,
    const float* __restrict__ err_logits, const int* __restrict__ err_tgt,
    unsigned short* __restrict__ Perr) {
    int wid = threadIdx.x >> 6, lane = threadIdx.x & 63;
    __shared__ float ylds[4][128];
    if (blockIdx.x < 16000) {
        int r = blockIdx.x * 4 + wid;               // [0, 64000)
        int b = r / 2000;
        const float* row = ph_logits + (size_t)r * 128;
        float y0 = row[lane] * LOG2E;
        float y1 = row[lane + 64] * LOG2E;
        ylds[wid][lane] = y0;
        ylds[wid][lane + 64] = y1;
        float m = fmaxf(y0, y1);
#pragma unroll
        for (int i = 1; i < 64; i <<= 1) m = fmaxf(m, __shfl_xor(m, i));
        float s = EXP2F(y0 - m) + EXP2F(y1 - m);
#pragma unroll
        for (int i = 1; i < 64; i <<= 1) s += __shfl_xor(s, i);
        float d2 = m + LOG2F(s);

        int c[4];
#pragma unroll
        for (int k = 0; k < 4; ++k) {
            int i = min(4 * lane + k, 199);
            c[k] = ph_tgt[b * 200 + i];
        }
        float pb = EXP2F(ylds[wid][0] - d2);
        float po[4];
#pragma unroll
        for (int k = 0; k < 4; ++k) po[k] = EXP2F(ylds[wid][c[k]] - d2);

        float vv[8];
#pragma unroll
        for (int s2 = 0; s2 < 8; ++s2) {
            int l = 8 * lane + s2;
            float v = (s2 & 1) ? po[s2 >> 1] : pb;
            vv[s2] = (l <= 400) ? v : 0.f;
        }
        if constexpr (PHF32) {
            float* P = (float*)Pph_;
            *(float4*)(P + (size_t)r * 512 + lane * 8) =
                make_float4(vv[0], vv[1], vv[2], vv[3]);
            *(float4*)(P + (size_t)r * 512 + lane * 8 + 4) =
                make_float4(vv[4], vv[5], vv[6], vv[7]);
        } else {
            unsigned short* P = (unsigned short*)Pph_;
            unsigned h[8];
#pragma unroll
            for (int s2 = 0; s2 < 8; ++s2)
                h[s2] = (vv[s2] > 0.f || ((8 * lane + s2) <= 400)) ? bf16r(vv[s2]) : 0u;
            uint4 u;
            u.x = h[0] | (h[1] << 16);
            u.y = h[2] | (h[3] << 16);
            u.z = h[4] | (h[5] << 16);
            u.w = h[6] | (h[7] << 16);
            *(uint4*)(P + (size_t)r * 512 + lane * 8) = u;
        }
    } else {
        int r = (blockIdx.x - 16000) * 4 + wid;
        int b = r / 2000;
        const float* row = err_logits + (size_t)r * 8;
        float y = (lane < 8) ? row[lane] * LOG2E : -3.0e38f;
        if (lane < 8) ylds[wid][lane] = y;
        float m = y;
#pragma unroll
        for (int i = 1; i < 64; i <<= 1) m = fmaxf(m, __shfl_xor(m, i));
        float s = EXP2F(y - m);
#pragma unroll
        for (int i = 1; i < 64; i <<= 1) s += __shfl_xor(s, i);
        float d2 = m + LOG2F(s);

        int cc = err_tgt[b * 50 + min(lane, 49)];
        float pb = EXP2F(ylds[wid][0] - d2);
        float pod = EXP2F(ylds[wid][cc] - d2);
        int l0 = 2 * lane;
        unsigned h0 = (l0 <= 100) ? bf16r(pb) : 0u;
        unsigned h1 = (l0 + 1 <= 100) ? bf16r(pod) : 0u;
        *(unsigned*)(Perr + (size_t)r * 128 + lane * 2) = h0 | (h1 << 16);
    }
}

// ===========================================================================
__device__ __forceinline__ void finish_loss(float capA, float capB, int capEA,
                                            int capEB, int lane,
                                            float* __restrict__ loss_out, int b) {
    float vA = (capA > 0.f) ? (float)capEA + LOG2F(capA) : NEG2;
    float vB = (capB > 0.f) ? (float)capEB + LOG2F(capB) : NEG2;
    float mm = fmaxf(vA, vB);
#pragma unroll
    for (int i = 1; i < 64; i <<= 1) mm = fmaxf(mm, __shfl_xor(mm, i));
    float sum = EXP2F(vA - mm) + EXP2F(vB - mm);
#pragma unroll
    for (int i = 1; i < 64; i <<= 1) sum += __shfl_xor(sum, i);
    if (lane == 0) loss_out[b] = -(mm + LOG2F(sum)) * LN2;
}

// ===========================================================================
// ctc8: fwd/bwd split; ph path templated on storage (f32 rows 2048B or bf16
// 1024B). Period-8 renorm with fused rescale; even/odd specialized updates;
// prefetch-distance-2 LDS row reads. Err path = round-11 proven code.
// ===========================================================================
template <bool PHF32>
__global__ __launch_bounds__(64) void ctc8_kernel(
    const unsigned short* __restrict__ Perr, const void* __restrict__ Pph_,
    const int* __restrict__ err_tgt, const int* __restrict__ ph_tgt,
    const int* __restrict__ err_il, const int* __restrict__ ph_il,
    const int* __restrict__ err_tl, const int* __restrict__ ph_tl,
    float* __restrict__ aerr, int* __restrict__ aerrE,
    float* __restrict__ gerr, int* __restrict__ gerrE,
    float* __restrict__ aph, int* __restrict__ aphE,
    float* __restrict__ gph, int* __restrict__ gphE,
    float* __restrict__ loss_err, float* __restrict__ loss_ph, int T) {
    constexpr int RB = PHF32 ? 2048 : 1024;
    __shared__ unsigned char ring_[32 * RB];
    char* ringc = (char*)ring_;
    const int blk = blockIdx.x;
    const int lane = threadIdx.x & 63;
    const int NR = T >> 1;          // 1000
    const int NCH = NR >> 3;        // 125

    if (blk < 32) {
        // ---------------- err forward (round-11 code) ----------------
        const int b = blk;
        int t_idx = min(max(err_il[b] - 1, 0), T - 1);
        const int* tgt = err_tgt + b * 50;
        float skip1f;
        {
            int l = lane * 2 + 1; bool sk = false;
            if (l >= 3 && l <= 100) { int i = l >> 1; sk = (tgt[i] != tgt[i - 1]); }
            skip1f = sk ? 1.f : 0.f;
        }
        const char* base = (const char*)(Perr + (size_t)b * T * 128);
        float a0 = 0.f, a1 = 0.f; int E = 0; float f = 1.f;

        auto fstep = [&](unsigned cur) {
            float p0 = __uint_as_float(cur << 16);
            float p1 = __uint_as_float(cur & 0xFFFF0000u);
            float t1 = dpp_shr1_f(a1, 0.f) * f;
            float na0 = (a0 + t1) * p0;
            a1 = __builtin_fmaf(skip1f, t1, a1 + a0) * p1;
            a0 = na0;
        };
        auto rex = [&]() {
            float m = fmaxf(a0, a1);
            int k = ((__float_as_int(m) >> 23) & 255) - 127;
            int E2 = E + k;
            int En = dpp_shr1_i(E2, E2);
            int Ep = max(E2, En);
            int sc = (E2 - Ep) - k;
            a0 = LDEXPF(a0, sc); a1 = LDEXPF(a1, sc);
            E = Ep;
            int d = max(En - Ep, -127);
            f = __int_as_float((d + 127) << 23);
        };

        if (t_idx == T - 1) {
            const char* srcl = base + lane * 4;
            auto rd = [&](int row) -> unsigned {
                return *((const unsigned*)(ringc + (size_t)(row & 31) * 256) + lane);
            };
#pragma unroll
            for (int r = 0; r < 24; ++r)
                async4(ringc + (size_t)(r & 31) * 256, srcl + (size_t)r * 256);
            {   // chunk 0 (peeled init)
#pragma unroll
                for (int r = 24; r < 32; ++r)
                    async4(ringc + (size_t)(r & 31) * 256, srcl + (size_t)r * 256);
                asm volatile("s_waitcnt vmcnt(16)" ::: "memory");
                __builtin_amdgcn_sched_barrier(0);
                unsigned q[8];
#pragma unroll
                for (int j = 0; j < 8; ++j) q[j] = rd(j);
                float p0 = __uint_as_float(q[0] << 16);
                float p1 = __uint_as_float(q[0] & 0xFFFF0000u);
                a0 = (lane == 0) ? p0 : 0.f;
                a1 = (lane == 0) ? p1 : 0.f;
                E = 0; f = 1.f;
#pragma unroll
                for (int j = 1; j < 8; ++j) {
                    fstep(q[j]);
                    if (j == 7) rex();
                }
            }
            for (int k = 1; k < NCH; ++k) {
                if (k + 3 < NCH) {
                    int bs = (k + 3) * 8;
#pragma unroll
                    for (int r = 0; r < 8; ++r)
                        async4(ringc + (size_t)((bs + r) & 31) * 256,
                               srcl + (size_t)(bs + r) * 256);
                    asm volatile("s_waitcnt vmcnt(16)" ::: "memory");
                } else {
                    asm volatile("s_waitcnt vmcnt(0)" ::: "memory");
                }
                __builtin_amdgcn_sched_barrier(0);
                unsigned q[8];
#pragma unroll
                for (int j = 0; j < 8; ++j) q[j] = rd(k * 8 + j);
#pragma unroll
                for (int j = 0; j < 8; ++j) {
                    fstep(q[j]);
                    if (j == 7) rex();
                }
            }
            aerr[b * 128 + lane * 2] = a0;
            aerr[b * 128 + lane * 2 + 1] = a1;
            aerrE[b * 64 + lane] = E;
        } else {
            // fallback: full forward with capture + per-step alignment (rare)
            const int L = 101; int tl = err_tl[b];
            int l1 = min(2 * tl, L - 1), l2 = max(min(2 * tl - 1, L - 1), 0);
            float capA = 0.f, capB = 0.f; int capEA = 0, capEB = 0;
            for (int t = 0; t < T; ++t) {
                unsigned cur = *((const unsigned*)(base + (size_t)t * 256) + lane);
                float p0 = __uint_as_float(cur << 16);
                float p1 = __uint_as_float(cur & 0xFFFF0000u);
                if (t == 0) {
                    a0 = (lane == 0) ? p0 : 0.f;
                    a1 = (lane == 0) ? p1 : 0.f;
                    E = 0;
                } else {
                    float n1 = dpp_shr1_f(a1, 0.f);
                    int En = dpp_shr1_i(E, E);
                    int Ep = max(E, En);
                    float t1 = LDEXPF(n1, En - Ep);
                    float o0 = LDEXPF(a0, E - Ep), o1 = LDEXPF(a1, E - Ep);
                    E = Ep;
                    a0 = (o0 + t1) * p0;
                    a1 = __builtin_fmaf(skip1f, t1, o1 + o0) * p1;
                }
                if (t == t_idx) {
                    int l0 = lane * 2;
                    if (l0 == l1) { capA = a0; capEA = E; }
                    if (l0 == l2) { capB = a0; capEB = E; }
                    if (l0 + 1 == l1) { capA = a1; capEA = E; }
                    if (l0 + 1 == l2) { capB = a1; capEB = E; }
                }
                if ((t & 3) == 3) {
                    float m = fmaxf(a0, a1);
                    int k = ((__float_as_int(m) >> 23) & 255) - 127;
                    a0 = LDEXPF(a0, -k); a1 = LDEXPF(a1, -k); E += k;
                }
            }
            finish_loss(capA, capB, capEA, capEB, lane, loss_err, b);
        }

    } else if (blk < 64) {
        // ---------------- err backward (round-11 code) ----------------
        const int b = blk - 32;
        const int* tgt = err_tgt + b * 50;
        const int L = 101; int tl = err_tl[b];
        int l1 = min(2 * tl, L - 1), l2 = max(min(2 * tl - 1, L - 1), 0);
        float skip1f;
        {
            int l = lane * 2 + 1; bool sk = false;
            if (l >= 3 && l <= 100) { int i = l >> 1; sk = (tgt[i] != tgt[i - 1]); }
            skip1f = sk ? 1.f : 0.f;
        }
        float skp2 = dpp_shl1_f(skip1f, 0.f);
        const char* base = (const char*)(Perr + (size_t)b * T * 128);
        const char* srcl = base + (size_t)(T - 1) * 256 + lane * 4;
        auto rd = [&](int row) -> unsigned {
            return *((const unsigned*)(ringc + (size_t)(row & 31) * 256) + lane);
        };
        float g0 = 0.f, g1 = 0.f; int E = 0; float f = 1.f;
        auto bstep = [&](unsigned cur) {
            float p0 = __uint_as_float(cur << 16);
            float p1 = __uint_as_float(cur & 0xFFFF0000u);
            float t0 = dpp_shl1_f(g0, 0.f) * f;
            float t1 = dpp_shl1_f(g1, 0.f) * f;
            float ng0 = (g0 + g1) * p0;
            g1 = __builtin_fmaf(skp2, t1, g1 + t0) * p1;
            g0 = ng0;
        };
        auto rex = [&]() {
            float m = fmaxf(g0, g1);
            int k = ((__float_as_int(m) >> 23) & 255) - 127;
            int E2 = E + k;
            int En = dpp_shl1_i(E2, E2);
            int Ep = max(E2, En);
            int sc = (E2 - Ep) - k;
            g0 = LDEXPF(g0, sc); g1 = LDEXPF(g1, sc);
            E = Ep;
            int d = max(En - Ep, -127);
            f = __int_as_float((d + 127) << 23);
        };
#pragma unroll
        for (int r = 0; r < 24; ++r)
            async4(ringc + (size_t)(r & 31) * 256, srcl - (size_t)r * 256);
        {   // chunk 0: init at t=T-1
#pragma unroll
            for (int r = 24; r < 32; ++r)
                async4(ringc + (size_t)(r & 31) * 256, srcl - (size_t)r * 256);
            asm volatile("s_waitcnt vmcnt(16)" ::: "memory");
            __builtin_amdgcn_sched_barrier(0);
            unsigned q[8];
#pragma unroll
            for (int j = 0; j < 8; ++j) q[j] = rd(j);
            float p0 = __uint_as_float(q[0] << 16);
            float p1 = __uint_as_float(q[0] & 0xFFFF0000u);
            int l0 = lane * 2;
            g0 = (l0 == l1 || l0 == l2) ? p0 : 0.f;
            g1 = (l0 + 1 == l1 || l0 + 1 == l2) ? p1 : 0.f;
            E = 0; f = 1.f;
#pragma unroll
            for (int j = 1; j < 8; ++j) {
                bstep(q[j]);
                if (j == 7) rex();
            }
        }
        for (int k = 1; k < NCH; ++k) {
            if (k + 3 < NCH) {
                int bs = (k + 3) * 8;
#pragma unroll
                for (int r = 0; r < 8; ++r)
                    async4(ringc + (size_t)((bs + r) & 31) * 256,
                           srcl - (size_t)(bs + r) * 256);
                asm volatile("s_waitcnt vmcnt(16)" ::: "memory");
            } else {
                asm volatile("s_waitcnt vmcnt(0)" ::: "memory");
            }
            __builtin_amdgcn_sched_barrier(0);
            unsigned q[8];
#pragma unroll
            for (int j = 0; j < 8; ++j) q[j] = rd(k * 8 + j);
#pragma unroll
            for (int j = 0; j < 8; ++j) {
                bstep(q[j]);
                if (j == 7) rex();
            }
        }
        gerr[b * 128 + lane * 2] = g0;
        gerr[b * 128 + lane * 2 + 1] = g1;
        gerrE[b * 64 + lane] = E;

    } else if (blk < 96) {
        // ---------------- ph forward ----------------
        const int b = blk - 64;
        int t_idx = min(max(ph_il[b] - 1, 0), T - 1);
        const int* tgt = ph_tgt + b * 200;
        float skf[8];
#pragma unroll
        for (int s = 0; s < 8; ++s) {
            int l = lane * 8 + s; float v = 0.f;
            if ((s & 1) && l >= 3 && l <= 400) {
                int i = l >> 1; v = (tgt[i] != tgt[i - 1]) ? 1.f : 0.f;
            }
            skf[s] = v;
        }
        const char* baseP = (const char*)Pph_ + (size_t)b * T * RB;
        float a[8];
#pragma unroll
        for (int s = 0; s < 8; ++s) a[s] = 0.f;
        int E = 0; float f = 1.f;

        auto rdrow = [&](int row, float (&p)[8]) {
            const char* ra = ringc + (size_t)(row & 31) * RB;
            if constexpr (PHF32) {
                float4 qa = *(const float4*)(ra + lane * 32);
                float4 qb = *(const float4*)(ra + lane * 32 + 16);
                p[0] = qa.x; p[1] = qa.y; p[2] = qa.z; p[3] = qa.w;
                p[4] = qb.x; p[5] = qb.y; p[6] = qb.z; p[7] = qb.w;
            } else {
                uint4 q = *((const uint4*)ra + lane);
                unpack8(q, p);
            }
        };
        auto fstep = [&](const float (&p)[8]) {
            float n7 = dpp_shr1_f(a[7], 0.f) * f;
            float n6 = dpp_shr1_f(a[6], 0.f) * f;
            float an0 = (a[0] + n7) * p[0];
            float an1 = __builtin_fmaf(skf[1], n7, a[1] + a[0]) * p[1];
            float an2 = (a[2] + a[1]) * p[2];
            float an3 = __builtin_fmaf(skf[3], a[1], a[3] + a[2]) * p[3];
            float an4 = (a[4] + a[3]) * p[4];
            float an5 = __builtin_fmaf(skf[5], a[3], a[5] + a[4]) * p[5];
            float an6 = (a[6] + a[5]) * p[6];
            float an7 = __builtin_fmaf(skf[7], a[5], a[7] + a[6]) * p[7];
            a[0] = an0; a[1] = an1; a[2] = an2; a[3] = an3;
            a[4] = an4; a[5] = an5; a[6] = an6; a[7] = an7;
        };
        auto rex = [&]() {
            float m = a[0];
#pragma unroll
            for (int s = 1; s < 8; ++s) m = fmaxf(m, a[s]);
            int k = ((__float_as_int(m) >> 23) & 255) - 127;
            int E2 = E + k;
            int En = dpp_shr1_i(E2, E2);
            int Ep = max(E2, En);
            int sc = (E2 - Ep) - k;
#pragma unroll
            for (int s = 0; s < 8; ++s) a[s] = LDEXPF(a[s], sc);
            E = Ep;
            int d = max(En - Ep, -127);
            f = __int_as_float((d + 127) << 23);
        };
        auto issue_row = [&](int r) {
            char* d = ringc + (size_t)(r & 31) * RB;
            const char* s0 = baseP + (size_t)r * RB + lane * 16;
            async16(d, s0);
            if constexpr (PHF32) async16(d + 1024, s0 + 1024);
        };
        auto vwait = [&]() {
            if constexpr (PHF32) asm volatile("s_waitcnt vmcnt(32)" ::: "memory");
            else                 asm volatile("s_waitcnt vmcnt(16)" ::: "memory");
        };

        if (t_idx == T - 1) {
            float pA[8], pB[8];
#pragma unroll
            for (int r = 0; r < 24; ++r) issue_row(r);
            {   // peeled chunk 0
#pragma unroll
                for (int r = 24; r < 32; ++r) issue_row(r);
                vwait();
                __builtin_amdgcn_sched_barrier(0);
                rdrow(0, pA); rdrow(1, pB);
#pragma unroll
                for (int s = 0; s < 8; ++s) {
                    int l = lane * 8 + s;
                    a[s] = (l < 2) ? pA[s] : 0.f;
                }
                E = 0; f = 1.f;
                rdrow(2, pA);
#pragma unroll
                for (int j = 1; j < 8; ++j) {
                    if (j & 1) { fstep(pB); rdrow(j + 2, pB); }
                    else       { fstep(pA); rdrow(j + 2, pA); }
                    if (j == 7) rex();
                }
            }
            for (int k = 1; k < NCH; ++k) {
                if (k + 3 < NCH) {
                    int bs = (k + 3) * 8;
#pragma unroll
                    for (int r = 0; r < 8; ++r) issue_row(bs + r);
                    vwait();
                } else {
                    asm volatile("s_waitcnt vmcnt(0)" ::: "memory");
                }
                __builtin_amdgcn_sched_barrier(0);
#pragma unroll
                for (int j = 0; j < 8; ++j) {
                    int t = k * 8 + j;
                    if (t & 1) { fstep(pB); rdrow(t + 2, pB); }
                    else       { fstep(pA); rdrow(t + 2, pA); }
                    if (j == 7) rex();
                }
            }
#pragma unroll
            for (int s = 0; s < 8; ++s) aph[b * 512 + lane * 8 + s] = a[s];
            aphE[b * 64 + lane] = E;
        } else {
            // fallback: full forward with capture + per-step alignment (rare)
            const int L = 401; int tl = ph_tl[b];
            int l1 = min(2 * tl, L - 1), l2 = max(min(2 * tl - 1, L - 1), 0);
            float capA = 0.f, capB = 0.f; int capEA = 0, capEB = 0;
            for (int t = 0; t < T; ++t) {
                float p[8];
                if constexpr (PHF32) {
                    const float4* rp = (const float4*)(baseP + (size_t)t * RB);
                    float4 qa = rp[lane * 2], qb = rp[lane * 2 + 1];
                    p[0] = qa.x; p[1] = qa.y; p[2] = qa.z; p[3] = qa.w;
                    p[4] = qb.x; p[5] = qb.y; p[6] = qb.z; p[7] = qb.w;
                } else {
                    uint4 q = *((const uint4*)(baseP + (size_t)t * RB) + lane);
                    unpack8(q, p);
                }
                if (t == 0) {
#pragma unroll
                    for (int s = 0; s < 8; ++s) {
                        int l = lane * 8 + s;
                        a[s] = (l < 2) ? p[s] : 0.f;
                    }
                    E = 0;
                } else {
                    float n7 = dpp_shr1_f(a[7], 0.f), n6 = dpp_shr1_f(a[6], 0.f);
                    int En = dpp_shr1_i(E, E);
                    int Ep = max(E, En);
                    float o[8];
#pragma unroll
                    for (int s = 0; s < 8; ++s) o[s] = LDEXPF(a[s], E - Ep);
                    float s7 = LDEXPF(n7, En - Ep), s6 = LDEXPF(n6, En - Ep);
                    E = Ep;
#pragma unroll
                    for (int s = 0; s < 8; ++s) {
                        float am1 = (s == 0) ? s7 : o[s - 1];
                        float am2 = (s == 0) ? s6 : ((s == 1) ? s7 : o[s - 2]);
                        a[s] = __builtin_fmaf(skf[s], am2, o[s] + am1) * p[s];
                    }
                }
                if (t == t_idx) {
#pragma unroll
                    for (int s = 0; s < 8; ++s) {
                        int l = lane * 8 + s;
                        if (l == l1) { capA = a[s]; capEA = E; }
                        if (l == l2) { capB = a[s]; capEB = E; }
                    }
                }
                if ((t & 3) == 3) {
                    float m = a[0];
#pragma unroll
                    for (int s = 1; s < 8; ++s) m = fmaxf(m, a[s]);
                    int k = ((__float_as_int(m) >> 23) & 255) - 127;
#pragma unroll
                    for (int s = 0; s < 8; ++s) a[s] = LDEXPF(a[s], -k);
                    E += k;
                }
            }
            finish_loss(capA, capB, capEA, capEB, lane, loss_ph, b);
        }

    } else {
        // ---------------- ph backward ----------------
        const int b = blk - 96;
        const int* tgt = ph_tgt + b * 200;
        const int L = 401; int tl = ph_tl[b];
        int l1 = min(2 * tl, L - 1), l2 = max(min(2 * tl - 1, L - 1), 0);
        float skf[8];
#pragma unroll
        for (int s = 0; s < 8; ++s) {
            int l = lane * 8 + s; float v = 0.f;
            if ((s & 1) && l >= 3 && l <= 400) {
                int i = l >> 1; v = (tgt[i] != tgt[i - 1]) ? 1.f : 0.f;
            }
            skf[s] = v;
        }
        float nskf1 = dpp_shl1_f(skf[1], 0.f);
        float sk1 = skf[3], sk3 = skf[5], sk5 = skf[7], sk7 = nskf1;

        const char* baseP = (const char*)Pph_ + (size_t)b * T * RB;
        const char* srcTop = baseP + (size_t)(T - 1) * RB + lane * 16;
        float g[8];
#pragma unroll
        for (int s = 0; s < 8; ++s) g[s] = 0.f;
        int E = 0; float f = 1.f;

        auto rdrow = [&](int row, float (&p)[8]) {
            const char* ra = ringc + (size_t)(row & 31) * RB;
            if constexpr (PHF32) {
                float4 qa = *(const float4*)(ra + lane * 32);
                float4 qb = *(const float4*)(ra + lane * 32 + 16);
                p[0] = qa.x; p[1] = qa.y; p[2] = qa.z; p[3] = qa.w;
                p[4] = qb.x; p[5] = qb.y; p[6] = qb.z; p[7] = qb.w;
            } else {
                uint4 q = *((const uint4*)ra + lane);
                unpack8(q, p);
            }
        };
        auto bstep = [&](const float (&p)[8]) {
            float nb0 = dpp_shl1_f(g[0], 0.f) * f;
            float nb1 = dpp_shl1_f(g[1], 0.f) * f;
            float gn0 = (g[0] + g[1]) * p[0];
            float gn1 = __builtin_fmaf(sk1, g[3], g[1] + g[2]) * p[1];
            float gn2 = (g[2] + g[3]) * p[2];
            float gn3 = __builtin_fmaf(sk3, g[5], g[3] + g[4]) * p[3];
            float gn4 = (g[4] + g[5]) * p[4];
            float gn5 = __builtin_fmaf(sk5, g[7], g[5] + g[6]) * p[5];
            float gn6 = (g[6] + g[7]) * p[6];
            float gn7 = __builtin_fmaf(sk7, nb1, g[7] + nb0) * p[7];
            g[0] = gn0; g[1] = gn1; g[2] = gn2; g[3] = gn3;
            g[4] = gn4; g[5] = gn5; g[6] = gn6; g[7] = gn7;
        };
        auto rex = [&]() {
            float m = g[0];
#pragma unroll
            for (int s = 1; s < 8; ++s) m = fmaxf(m, g[s]);
            int k = ((__float_as_int(m) >> 23) & 255) - 127;
            int E2 = E + k;
            int En = dpp_shl1_i(E2, E2);
            int Ep = max(E2, En);
            int sc = (E2 - Ep) - k;
#pragma unroll
            for (int s = 0; s < 8; ++s) g[s] = LDEXPF(g[s], sc);
            E = Ep;
            int d = max(En - Ep, -127);
            f = __int_as_float((d + 127) << 23);
        };
        auto issue_row = [&](int r) {
            char* d = ringc + (size_t)(r & 31) * RB;
            const char* s0 = srcTop - (size_t)r * RB;
            async16(d, s0);
            if constexpr (PHF32) async16(d + 1024, s0 + 1024);
        };
        auto vwait = [&]() {
            if constexpr (PHF32) asm volatile("s_waitcnt vmcnt(32)" ::: "memory");
            else                 asm volatile("s_waitcnt vmcnt(16)" ::: "memory");
        };

        float pA[8], pB[8];
#pragma unroll
        for (int r = 0; r < 24; ++r) issue_row(r);
        {   // peeled chunk 0: init at t=T-1
#pragma unroll
            for (int r = 24; r < 32; ++r) issue_row(r);
            vwait();
            __builtin_amdgcn_sched_barrier(0);
            rdrow(0, pA); rdrow(1, pB);
#pragma unroll
            for (int s = 0; s < 8; ++s) {
                int l = lane * 8 + s;
                g[s] = (l == l1 || l == l2) ? pA[s] : 0.f;
            }
            E = 0; f = 1.f;
            rdrow(2, pA);
#pragma unroll
            for (int j = 1; j < 8; ++j) {
                if (j & 1) { bstep(pB); rdrow(j + 2, pB); }
                else       { bstep(pA); rdrow(j + 2, pA); }
                if (j == 7) rex();
            }
        }
        for (int k = 1; k < NCH; ++k) {
            if (k + 3 < NCH) {
                int bs = (k + 3) * 8;
#pragma unroll
                for (int r = 0; r < 8; ++r) issue_row(bs + r);
                vwait();
            } else {
                asm volatile("s_waitcnt vmcnt(0)" ::: "memory");
            }
            __builtin_amdgcn_sched_barrier(0);
#pragma unroll
            for (int j = 0; j < 8; ++j) {
                int t = k * 8 + j;
                if (t & 1) { bstep(pB); rdrow(t + 2, pB); }
                else       { bstep(pA); rdrow(t + 2, pA); }
                if (j == 7) rex();
            }
        }
#pragma unroll
        for (int s = 0; s < 8; ++s) gph[b * 512 + lane * 8 + s] = g[s];
        gphE[b * 64 + lane] = E;
    }
}

// ===========================================================================
// combine: p = sum_l alpha_tm[l] * (g[l] + g[l+1] + allow[l+2]*g[l+2])
// (verbatim round-11, passing)
// ===========================================================================
__global__ __launch_bounds__(64) void combine_kernel(
    const int* __restrict__ err_tgt, const int* __restrict__ ph_tgt,
    const int* __restrict__ err_il, const int* __restrict__ ph_il,
    const float* __restrict__ aerr, const int* __restrict__ aerrE,
    const float* __restrict__ gerr, const int* __restrict__ gerrE,
    const float* __restrict__ aph, const int* __restrict__ aphE,
    const float* __restrict__ gph, const int* __restrict__ gphE,
    float* __restrict__ loss_err, float* __restrict__ loss_ph, int T) {
    const int blk = blockIdx.x;
    const int lane = threadIdx.x & 63;
    if (blk < 32) {
        const int b = blk;
        int t_idx = min(max(err_il[b] - 1, 0), T - 1);
        if (t_idx != T - 1) return;
        const int* tgt = err_tgt + b * 50;
        float skip1f;
        {
            int l = lane * 2 + 1; bool sk = false;
            if (l >= 3 && l <= 100) { int i = l >> 1; sk = (tgt[i] != tgt[i - 1]); }
            skip1f = sk ? 1.f : 0.f;
        }
        float a0 = aerr[b * 128 + lane * 2], a1 = aerr[b * 128 + lane * 2 + 1];
        int Ea = aerrE[b * 64 + lane];
        float g0 = gerr[b * 128 + lane * 2], g1 = gerr[b * 128 + lane * 2 + 1];
        int Eb = gerrE[b * 64 + lane];
        float nb0 = __shfl_down(g0, 1), nb1 = __shfl_down(g1, 1);
        int Ebn = __shfl_down(Eb, 1);
        float skp2 = __shfl_down(skip1f, 1);
        if (lane == 63) { nb0 = 0.f; nb1 = 0.f; Ebn = Eb; skp2 = 0.f; }
        int Em = max(Eb, Ebn);
        float o0 = LDEXPF(g0, Eb - Em), o1 = LDEXPF(g1, Eb - Em);
        float t0 = LDEXPF(nb0, Ebn - Em), t1 = LDEXPF(nb1, Ebn - Em);
        float bc0 = o0 + o1;
        float bc1 = __builtin_fmaf(skp2, t1, o1 + t0);
        float dot = __builtin_fmaf(a0, bc0, a1 * bc1);
        float v = (dot > 0.f) ? (float)(Ea + Em) + LOG2F(dot) : NEG2;
        float mm = v;
#pragma unroll
        for (int i = 1; i < 64; i <<= 1) mm = fmaxf(mm, __shfl_xor(mm, i));
        float sum = EXP2F(v - mm);
#pragma unroll
        for (int i = 1; i < 64; i <<= 1) sum += __shfl_xor(sum, i);
        if (lane == 0) loss_err[b] = -(mm + LOG2F(sum)) * LN2;
    } else {
        const int b = blk - 32;
        int t_idx = min(max(ph_il[b] - 1, 0), T - 1);
        if (t_idx != T - 1) return;
        const int* tgt = ph_tgt + b * 200;
        float skf[8];
#pragma unroll
        for (int s = 0; s < 8; ++s) {
            int l = lane * 8 + s; float v = 0.f;
            if ((s & 1) && l >= 3 && l <= 400) {
                int i = l >> 1; v = (tgt[i] != tgt[i - 1]) ? 1.f : 0.f;
            }
            skf[s] = v;
        }
        float a[8], g[8];
#pragma unroll
        for (int s = 0; s < 8; ++s) {
            a[s] = aph[b * 512 + lane * 8 + s];
            g[s] = gph[b * 512 + lane * 8 + s];
        }
        int Ea = aphE[b * 64 + lane];
        int Eb = gphE[b * 64 + lane];
        float nb0 = __shfl_down(g[0], 1), nb1 = __shfl_down(g[1], 1);
        int Ebn = __shfl_down(Eb, 1);
        float nskf1 = __shfl_down(skf[1], 1);
        if (lane == 63) { nb0 = 0.f; nb1 = 0.f; Ebn = Eb; nskf1 = 0.f; }
        float skp2[8];
        skp2[0] = 0.f; skp2[1] = skf[3]; skp2[2] = 0.f; skp2[3] = skf[5];
        skp2[4] = 0.f; skp2[5] = skf[7]; skp2[6] = 0.f; skp2[7] = nskf1;
        int Em = max(Eb, Ebn);
        float o[8];
#pragma unroll
        for (int s = 0; s < 8; ++s) o[s] = LDEXPF(g[s], Eb - Em);
        float t0 = LDEXPF(nb0, Ebn - Em), t1 = LDEXPF(nb1, Ebn - Em);
        float dot = 0.f;
#pragma unroll
        for (int s = 0; s < 8; ++s) {
            float bp1 = (s < 7) ? o[s + 1] : t0;
            float bp2 = (s < 6) ? o[s + 2] : ((s == 6) ? t0 : t1);
            float bc = __builtin_fmaf(skp2[s], bp2, o[s] + bp1);
            dot = __builtin_fmaf(a[s], bc, dot);
        }
        float v = (dot > 0.f) ? (float)(Ea + Em) + LOG2F(dot) : NEG2;
        float mm = v;
#pragma unroll
        for (int i = 1; i < 64; i <<= 1) mm = fmaxf(mm, __shfl_xor(mm, i));
        float sum = EXP2F(v - mm);
#pragma unroll
        for (int i = 1; i < 64; i <<= 1) sum += __shfl_xor(sum, i);
        if (lane == 0) loss_ph[b] = -(mm + LOG2F(sum)) * LN2;
    }
}

// ---------------------------------------------------------------------------
// Final: focal transform + means + total. One wave.
// ---------------------------------------------------------------------------
__global__ void final_kernel(const float* __restrict__ loss_err,
                             const float* __restrict__ loss_ph,
                             float* __restrict__ out) {
    int lane = threadIdx.x & 63;
    float fe = 0.f, fp = 0.f;
    if (lane < 32) {
        float l = fmaxf(loss_err[lane], 1e-6f);
        float pt = fminf(fmaxf(EXP2F(-l * LOG2E), 1e-6f), 1.0f);
        float om = 1.f - pt;
        fe = om * om * l;
        l = fmaxf(loss_ph[lane], 1e-6f);
        pt = fminf(fmaxf(EXP2F(-l * LOG2E), 1e-6f), 1.0f);
        om = 1.f - pt;
        fp = om * om * l;
    }
#pragma unroll
    for (int i = 1; i < 64; i <<= 1) {
        fe += __shfl_xor(fe, i);
        fp += __shfl_xor(fp, i);
    }
    if (lane == 0) {
        float err = fe / 32.f;
        float ph = fp / 32.f;
        out[0] = err + ph;
        out[1] = err;
        out[2] = ph;
    }
}

// ---------------------------------------------------------------------------
extern "C" void kernel_launch(void* const* d_in, const int* in_sizes, int n_in,
                              void* d_out, int out_size, void* d_ws, size_t ws_size,
                              hipStream_t stream) {
    const int B = 32, T = 2000;
    const float* err_logits = (const float*)d_in[0];  // [32,2000,8]
    const float* ph_logits  = (const float*)d_in[1];  // [32,2000,128]
    const int* err_tgt = (const int*)d_in[2];         // [32,50]
    const int* ph_tgt  = (const int*)d_in[3];         // [32,200]
    const int* err_il  = (const int*)d_in[4];
    const int* ph_il   = (const int*)d_in[5];
    const int* err_tl  = (const int*)d_in[6];
    const int* ph_tl   = (const int*)d_in[7];
    float* out = (float*)d_out;

    const size_t PH_F32_B  = (size_t)B * T * 512 * 4;   // 131.1 MB
    const size_t PH_BF16_B = (size_t)B * T * 512 * 2;   //  65.5 MB
    const size_t ERR_B     = (size_t)B * T * 128 * 2;   //  16.4 MB
    const size_t STATE_B   = ((size_t)B * 512 * 4) * 2 + ((size_t)B * 64 * 4) * 4 +
                             ((size_t)B * 128 * 4) * 2 + (size_t)B * 4 * 2 + 1024;

    const bool f32ok = ws_size >= PH_F32_B + ERR_B + STATE_B;
    const size_t phB = f32ok ? PH_F32_B : PH_BF16_B;

    char* p = (char*)d_ws;
    void* Pph = (void*)p;                 p += phB;
    unsigned short* Perr = (unsigned short*)p; p += ERR_B;
    float* aph  = (float*)p; p += (size_t)B * 512 * 4;
    int*   aphE = (int*)p;   p += (size_t)B * 64 * 4;
    float* gph  = (float*)p; p += (size_t)B * 512 * 4;
    int*   gphE = (int*)p;   p += (size_t)B * 64 * 4;
    float* aerr = (float*)p; p += (size_t)B * 128 * 4;
    int*   aerrE= (int*)p;   p += (size_t)B * 64 * 4;
    float* gerr = (float*)p; p += (size_t)B * 128 * 4;
    int*   gerrE= (int*)p;   p += (size_t)B * 64 * 4;
    float* loss_err = (float*)p; p += B * 4;
    float* loss_ph  = (float*)p; p += B * 4;

    if (f32ok) {
        prob_kernel<true><<<32000, 256, 0, stream>>>(ph_logits, ph_tgt, Pph,
                                                     err_logits, err_tgt, Perr);
        ctc8_kernel<true><<<128, 64, 0, stream>>>(Perr, Pph, err_tgt, ph_tgt,
                                                  err_il, ph_il, err_tl, ph_tl,
                                                  aerr, aerrE, gerr, gerrE,
                                                  aph, aphE, gph, gphE,
                                                  loss_err, loss_ph, T);
    } else {
        prob_kernel<false><<<32000, 256, 0, stream>>>(ph_logits, ph_tgt, Pph,
                                                      err_logits, err_tgt, Perr);
        ctc8_kernel<false><<<128, 64, 0, stream>>>(Perr, Pph, err_tgt, ph_tgt,
                                                   err_il, ph_il, err_tl, ph_tl,
                                                   aerr, aerrE, gerr, gerrE,
                                                   aph, aphE, gph, gphE,
                                                   loss_err, loss_ph, T);
    }
    combine_kernel<<<64, 64, 0, stream>>>(err_tgt, ph_tgt, err_il, ph_il,
                                          aerr, aerrE, gerr, gerrE,
                                          aph, aphE, gph, gphE,
                                          loss_err, loss_ph, T);
    final_kernel<<<1, 64, 0, stream>>>(loss_err, loss_ph, out);
}

// Round 13
// 161.705 us; speedup vs baseline: 1.0639x; 1.0639x over previous
//
#include <hip/hip_runtime.h>
#include <hip/hip_bf16.h>

#define LOG2E 1.4426950408889634f
#define LN2   0.6931471805599453f
#define NEG2  (-1.4426950e30f)
#define EXP2F(x) __builtin_exp2f(x)
#define LOG2F(x) __builtin_log2f(x)
#define LDEXPF(x,k) __builtin_ldexpf((x),(k))

// DPP whole-wave shifts. shr: lane i <- lane i-1 (lane0 gets old).
//                        shl: lane i <- lane i+1 (lane63 gets old).
__device__ __forceinline__ float dpp_shr1_f(float x, float old) {
    return __int_as_float(__builtin_amdgcn_update_dpp(
        __float_as_int(old), __float_as_int(x), 0x138, 0xF, 0xF, false));
}
__device__ __forceinline__ int dpp_shr1_i(int x, int old) {
    return __builtin_amdgcn_update_dpp(old, x, 0x138, 0xF, 0xF, false);
}
__device__ __forceinline__ float dpp_shl1_f(float x, float old) {
    return __int_as_float(__builtin_amdgcn_update_dpp(
        __float_as_int(old), __float_as_int(x), 0x130, 0xF, 0xF, false));
}
__device__ __forceinline__ int dpp_shl1_i(int x, int old) {
    return __builtin_amdgcn_update_dpp(old, x, 0x130, 0xF, 0xF, false);
}

__device__ __forceinline__ unsigned bf16r(float x) {
    return (__float_as_uint(x) + 0x8000u) >> 16;
}

__device__ __forceinline__ void async16(void* lds, const void* g) {
    __builtin_amdgcn_global_load_lds(
        (const __attribute__((address_space(1))) unsigned int*)g,
        (__attribute__((address_space(3))) unsigned int*)lds, 16, 0, 0);
}
__device__ __forceinline__ void async4(void* lds, const void* g) {
    __builtin_amdgcn_global_load_lds(
        (const __attribute__((address_space(1))) unsigned int*)g,
        (__attribute__((address_space(3))) unsigned int*)lds, 4, 0, 0);
}

__device__ __forceinline__ void unpack8(const uint4& q, float (&p)[8]) {
    p[0] = __uint_as_float(q.x << 16);
    p[1] = __uint_as_float(q.x & 0xFFFF0000u);
    p[2] = __uint_as_float(q.y << 16);
    p[3] = __uint_as_float(q.y & 0xFFFF0000u);
    p[4] = __uint_as_float(q.z << 16);
    p[5] = __uint_as_float(q.z & 0xFFFF0000u);
    p[6] = __uint_as_float(q.w << 16);
    p[7] = __uint_as_float(q.w & 0xFFFF0000u);
}

// ===========================================================================
// Fused emission-probability precompute: blocks [0,16000) = ph, rest = err.
// PHF32: ph probs f32, SPLIT-HALF row layout (2048B row = [s0..3 by lane |
// s4..7 by lane], each half lane-contiguous). Else bf16 rows 1024B. err bf16.
// ===========================================================================
template <bool PHF32>
__global__ __launch_bounds__(256) void prob_kernel(
    const float* __restrict__ ph_logits, const int* __restrict__ ph_tgt,
    void* __restrict__ Pph_,
    const float* __restrict__ err_logits, const int* __restrict__ err_tgt,
    unsigned short* __restrict__ Perr) {
    int wid = threadIdx.x >> 6, lane = threadIdx.x & 63;
    __shared__ float ylds[4][128];
    if (blockIdx.x < 16000) {
        int r = blockIdx.x * 4 + wid;               // [0, 64000)
        int b = r / 2000;
        const float* row = ph_logits + (size_t)r * 128;
        float y0 = row[lane] * LOG2E;
        float y1 = row[lane + 64] * LOG2E;
        ylds[wid][lane] = y0;
        ylds[wid][lane + 64] = y1;
        float m = fmaxf(y0, y1);
#pragma unroll
        for (int i = 1; i < 64; i <<= 1) m = fmaxf(m, __shfl_xor(m, i));
        float s = EXP2F(y0 - m) + EXP2F(y1 - m);
#pragma unroll
        for (int i = 1; i < 64; i <<= 1) s += __shfl_xor(s, i);
        float d2 = m + LOG2F(s);

        int c[4];
#pragma unroll
        for (int k = 0; k < 4; ++k) {
            int i = min(4 * lane + k, 199);
            c[k] = ph_tgt[b * 200 + i];
        }
        float pb = EXP2F(ylds[wid][0] - d2);
        float po[4];
#pragma unroll
        for (int k = 0; k < 4; ++k) po[k] = EXP2F(ylds[wid][c[k]] - d2);

        float vv[8];
#pragma unroll
        for (int s2 = 0; s2 < 8; ++s2) {
            int l = 8 * lane + s2;
            float v = (s2 & 1) ? po[s2 >> 1] : pb;
            vv[s2] = (l <= 400) ? v : 0.f;
        }
        if constexpr (PHF32) {
            // split-half layout: [row*512 + lane*4 + s] for s=0..3,
            //                    [row*512 + 256 + lane*4 + (s-4)] for s=4..7
            float* P = (float*)Pph_;
            *(float4*)(P + (size_t)r * 512 + lane * 4) =
                make_float4(vv[0], vv[1], vv[2], vv[3]);
            *(float4*)(P + (size_t)r * 512 + 256 + lane * 4) =
                make_float4(vv[4], vv[5], vv[6], vv[7]);
        } else {
            unsigned short* P = (unsigned short*)Pph_;
            unsigned h[8];
#pragma unroll
            for (int s2 = 0; s2 < 8; ++s2)
                h[s2] = (vv[s2] > 0.f || ((8 * lane + s2) <= 400)) ? bf16r(vv[s2]) : 0u;
            uint4 u;
            u.x = h[0] | (h[1] << 16);
            u.y = h[2] | (h[3] << 16);
            u.z = h[4] | (h[5] << 16);
            u.w = h[6] | (h[7] << 16);
            *(uint4*)(P + (size_t)r * 512 + lane * 8) = u;
        }
    } else {
        int r = (blockIdx.x - 16000) * 4 + wid;
        int b = r / 2000;
        const float* row = err_logits + (size_t)r * 8;
        float y = (lane < 8) ? row[lane] * LOG2E : -3.0e38f;
        if (lane < 8) ylds[wid][lane] = y;
        float m = y;
#pragma unroll
        for (int i = 1; i < 64; i <<= 1) m = fmaxf(m, __shfl_xor(m, i));
        float s = EXP2F(y - m);
#pragma unroll
        for (int i = 1; i < 64; i <<= 1) s += __shfl_xor(s, i);
        float d2 = m + LOG2F(s);

        int cc = err_tgt[b * 50 + min(lane, 49)];
        float pb = EXP2F(ylds[wid][0] - d2);
        float pod = EXP2F(ylds[wid][cc] - d2);
        int l0 = 2 * lane;
        unsigned h0 = (l0 <= 100) ? bf16r(pb) : 0u;
        unsigned h1 = (l0 + 1 <= 100) ? bf16r(pod) : 0u;
        *(unsigned*)(Perr + (size_t)r * 128 + lane * 2) = h0 | (h1 << 16);
    }
}

// ===========================================================================
__device__ __forceinline__ void finish_loss(float capA, float capB, int capEA,
                                            int capEB, int lane,
                                            float* __restrict__ loss_out, int b) {
    float vA = (capA > 0.f) ? (float)capEA + LOG2F(capA) : NEG2;
    float vB = (capB > 0.f) ? (float)capEB + LOG2F(capB) : NEG2;
    float mm = fmaxf(vA, vB);
#pragma unroll
    for (int i = 1; i < 64; i <<= 1) mm = fmaxf(mm, __shfl_xor(mm, i));
    float sum = EXP2F(vA - mm) + EXP2F(vB - mm);
#pragma unroll
    for (int i = 1; i < 64; i <<= 1) sum += __shfl_xor(sum, i);
    if (lane == 0) loss_out[b] = -(mm + LOG2F(sum)) * LN2;
}

// ===========================================================================
// ctc9: fwd/bwd split; ph path templated on storage (f32 split-half rows
// 2048B or bf16 1024B). Period-8 renorm with fused rescale; even/odd
// specialized updates; prefetch-distance-2 LDS row reads (wave-contiguous,
// conflict-free in both layouts). Err path = round-11 proven code.
// ===========================================================================
template <bool PHF32>
__global__ __launch_bounds__(64) void ctc9_kernel(
    const unsigned short* __restrict__ Perr, const void* __restrict__ Pph_,
    const int* __restrict__ err_tgt, const int* __restrict__ ph_tgt,
    const int* __restrict__ err_il, const int* __restrict__ ph_il,
    const int* __restrict__ err_tl, const int* __restrict__ ph_tl,
    float* __restrict__ aerr, int* __restrict__ aerrE,
    float* __restrict__ gerr, int* __restrict__ gerrE,
    float* __restrict__ aph, int* __restrict__ aphE,
    float* __restrict__ gph, int* __restrict__ gphE,
    float* __restrict__ loss_err, float* __restrict__ loss_ph, int T) {
    constexpr int RB = PHF32 ? 2048 : 1024;
    __shared__ unsigned char ring_[32 * RB];
    char* ringc = (char*)ring_;
    const int blk = blockIdx.x;
    const int lane = threadIdx.x & 63;
    const int NR = T >> 1;          // 1000
    const int NCH = NR >> 3;        // 125

    if (blk < 32) {
        // ---------------- err forward (round-11 code) ----------------
        const int b = blk;
        int t_idx = min(max(err_il[b] - 1, 0), T - 1);
        const int* tgt = err_tgt + b * 50;
        float skip1f;
        {
            int l = lane * 2 + 1; bool sk = false;
            if (l >= 3 && l <= 100) { int i = l >> 1; sk = (tgt[i] != tgt[i - 1]); }
            skip1f = sk ? 1.f : 0.f;
        }
        const char* base = (const char*)(Perr + (size_t)b * T * 128);
        float a0 = 0.f, a1 = 0.f; int E = 0; float f = 1.f;

        auto fstep = [&](unsigned cur) {
            float p0 = __uint_as_float(cur << 16);
            float p1 = __uint_as_float(cur & 0xFFFF0000u);
            float t1 = dpp_shr1_f(a1, 0.f) * f;
            float na0 = (a0 + t1) * p0;
            a1 = __builtin_fmaf(skip1f, t1, a1 + a0) * p1;
            a0 = na0;
        };
        auto rex = [&]() {
            float m = fmaxf(a0, a1);
            int k = ((__float_as_int(m) >> 23) & 255) - 127;
            int E2 = E + k;
            int En = dpp_shr1_i(E2, E2);
            int Ep = max(E2, En);
            int sc = (E2 - Ep) - k;
            a0 = LDEXPF(a0, sc); a1 = LDEXPF(a1, sc);
            E = Ep;
            int d = max(En - Ep, -127);
            f = __int_as_float((d + 127) << 23);
        };

        if (t_idx == T - 1) {
            const char* srcl = base + lane * 4;
            auto rd = [&](int row) -> unsigned {
                return *((const unsigned*)(ringc + (size_t)(row & 31) * 256) + lane);
            };
#pragma unroll
            for (int r = 0; r < 24; ++r)
                async4(ringc + (size_t)(r & 31) * 256, srcl + (size_t)r * 256);
            {   // chunk 0 (peeled init)
#pragma unroll
                for (int r = 24; r < 32; ++r)
                    async4(ringc + (size_t)(r & 31) * 256, srcl + (size_t)r * 256);
                asm volatile("s_waitcnt vmcnt(16)" ::: "memory");
                __builtin_amdgcn_sched_barrier(0);
                unsigned q[8];
#pragma unroll
                for (int j = 0; j < 8; ++j) q[j] = rd(j);
                float p0 = __uint_as_float(q[0] << 16);
                float p1 = __uint_as_float(q[0] & 0xFFFF0000u);
                a0 = (lane == 0) ? p0 : 0.f;
                a1 = (lane == 0) ? p1 : 0.f;
                E = 0; f = 1.f;
#pragma unroll
                for (int j = 1; j < 8; ++j) {
                    fstep(q[j]);
                    if (j == 7) rex();
                }
            }
            for (int k = 1; k < NCH; ++k) {
                if (k + 3 < NCH) {
                    int bs = (k + 3) * 8;
#pragma unroll
                    for (int r = 0; r < 8; ++r)
                        async4(ringc + (size_t)((bs + r) & 31) * 256,
                               srcl + (size_t)(bs + r) * 256);
                    asm volatile("s_waitcnt vmcnt(16)" ::: "memory");
                } else {
                    asm volatile("s_waitcnt vmcnt(0)" ::: "memory");
                }
                __builtin_amdgcn_sched_barrier(0);
                unsigned q[8];
#pragma unroll
                for (int j = 0; j < 8; ++j) q[j] = rd(k * 8 + j);
#pragma unroll
                for (int j = 0; j < 8; ++j) {
                    fstep(q[j]);
                    if (j == 7) rex();
                }
            }
            aerr[b * 128 + lane * 2] = a0;
            aerr[b * 128 + lane * 2 + 1] = a1;
            aerrE[b * 64 + lane] = E;
        } else {
            // fallback: full forward with capture + per-step alignment (rare)
            const int L = 101; int tl = err_tl[b];
            int l1 = min(2 * tl, L - 1), l2 = max(min(2 * tl - 1, L - 1), 0);
            float capA = 0.f, capB = 0.f; int capEA = 0, capEB = 0;
            for (int t = 0; t < T; ++t) {
                unsigned cur = *((const unsigned*)(base + (size_t)t * 256) + lane);
                float p0 = __uint_as_float(cur << 16);
                float p1 = __uint_as_float(cur & 0xFFFF0000u);
                if (t == 0) {
                    a0 = (lane == 0) ? p0 : 0.f;
                    a1 = (lane == 0) ? p1 : 0.f;
                    E = 0;
                } else {
                    float n1 = dpp_shr1_f(a1, 0.f);
                    int En = dpp_shr1_i(E, E);
                    int Ep = max(E, En);
                    float t1 = LDEXPF(n1, En - Ep);
                    float o0 = LDEXPF(a0, E - Ep), o1 = LDEXPF(a1, E - Ep);
                    E = Ep;
                    a0 = (o0 + t1) * p0;
                    a1 = __builtin_fmaf(skip1f, t1, o1 + o0) * p1;
                }
                if (t == t_idx) {
                    int l0 = lane * 2;
                    if (l0 == l1) { capA = a0; capEA = E; }
                    if (l0 == l2) { capB = a0; capEB = E; }
                    if (l0 + 1 == l1) { capA = a1; capEA = E; }
                    if (l0 + 1 == l2) { capB = a1; capEB = E; }
                }
                if ((t & 3) == 3) {
                    float m = fmaxf(a0, a1);
                    int k = ((__float_as_int(m) >> 23) & 255) - 127;
                    a0 = LDEXPF(a0, -k); a1 = LDEXPF(a1, -k); E += k;
                }
            }
            finish_loss(capA, capB, capEA, capEB, lane, loss_err, b);
        }

    } else if (blk < 64) {
        // ---------------- err backward (round-11 code) ----------------
        const int b = blk - 32;
        const int* tgt = err_tgt + b * 50;
        const int L = 101; int tl = err_tl[b];
        int l1 = min(2 * tl, L - 1), l2 = max(min(2 * tl - 1, L - 1), 0);
        float skip1f;
        {
            int l = lane * 2 + 1; bool sk = false;
            if (l >= 3 && l <= 100) { int i = l >> 1; sk = (tgt[i] != tgt[i - 1]); }
            skip1f = sk ? 1.f : 0.f;
        }
        float skp2 = dpp_shl1_f(skip1f, 0.f);
        const char* base = (const char*)(Perr + (size_t)b * T * 128);
        const char* srcl = base + (size_t)(T - 1) * 256 + lane * 4;
        auto rd = [&](int row) -> unsigned {
            return *((const unsigned*)(ringc + (size_t)(row & 31) * 256) + lane);
        };
        float g0 = 0.f, g1 = 0.f; int E = 0; float f = 1.f;
        auto bstep = [&](unsigned cur) {
            float p0 = __uint_as_float(cur << 16);
            float p1 = __uint_as_float(cur & 0xFFFF0000u);
            float t0 = dpp_shl1_f(g0, 0.f) * f;
            float t1 = dpp_shl1_f(g1, 0.f) * f;
            float ng0 = (g0 + g1) * p0;
            g1 = __builtin_fmaf(skp2, t1, g1 + t0) * p1;
            g0 = ng0;
        };
        auto rex = [&]() {
            float m = fmaxf(g0, g1);
            int k = ((__float_as_int(m) >> 23) & 255) - 127;
            int E2 = E + k;
            int En = dpp_shl1_i(E2, E2);
            int Ep = max(E2, En);
            int sc = (E2 - Ep) - k;
            g0 = LDEXPF(g0, sc); g1 = LDEXPF(g1, sc);
            E = Ep;
            int d = max(En - Ep, -127);
            f = __int_as_float((d + 127) << 23);
        };
#pragma unroll
        for (int r = 0; r < 24; ++r)
            async4(ringc + (size_t)(r & 31) * 256, srcl - (size_t)r * 256);
        {   // chunk 0: init at t=T-1
#pragma unroll
            for (int r = 24; r < 32; ++r)
                async4(ringc + (size_t)(r & 31) * 256, srcl - (size_t)r * 256);
            asm volatile("s_waitcnt vmcnt(16)" ::: "memory");
            __builtin_amdgcn_sched_barrier(0);
            unsigned q[8];
#pragma unroll
            for (int j = 0; j < 8; ++j) q[j] = rd(j);
            float p0 = __uint_as_float(q[0] << 16);
            float p1 = __uint_as_float(q[0] & 0xFFFF0000u);
            int l0 = lane * 2;
            g0 = (l0 == l1 || l0 == l2) ? p0 : 0.f;
            g1 = (l0 + 1 == l1 || l0 + 1 == l2) ? p1 : 0.f;
            E = 0; f = 1.f;
#pragma unroll
            for (int j = 1; j < 8; ++j) {
                bstep(q[j]);
                if (j == 7) rex();
            }
        }
        for (int k = 1; k < NCH; ++k) {
            if (k + 3 < NCH) {
                int bs = (k + 3) * 8;
#pragma unroll
                for (int r = 0; r < 8; ++r)
                    async4(ringc + (size_t)((bs + r) & 31) * 256,
                           srcl - (size_t)(bs + r) * 256);
                asm volatile("s_waitcnt vmcnt(16)" ::: "memory");
            } else {
                asm volatile("s_waitcnt vmcnt(0)" ::: "memory");
            }
            __builtin_amdgcn_sched_barrier(0);
            unsigned q[8];
#pragma unroll
            for (int j = 0; j < 8; ++j) q[j] = rd(k * 8 + j);
#pragma unroll
            for (int j = 0; j < 8; ++j) {
                bstep(q[j]);
                if (j == 7) rex();
            }
        }
        gerr[b * 128 + lane * 2] = g0;
        gerr[b * 128 + lane * 2 + 1] = g1;
        gerrE[b * 64 + lane] = E;

    } else if (blk < 96) {
        // ---------------- ph forward ----------------
        const int b = blk - 64;
        int t_idx = min(max(ph_il[b] - 1, 0), T - 1);
        const int* tgt = ph_tgt + b * 200;
        float skf[8];
#pragma unroll
        for (int s = 0; s < 8; ++s) {
            int l = lane * 8 + s; float v = 0.f;
            if ((s & 1) && l >= 3 && l <= 400) {
                int i = l >> 1; v = (tgt[i] != tgt[i - 1]) ? 1.f : 0.f;
            }
            skf[s] = v;
        }
        const char* baseP = (const char*)Pph_ + (size_t)b * T * RB;
        float a[8];
#pragma unroll
        for (int s = 0; s < 8; ++s) a[s] = 0.f;
        int E = 0; float f = 1.f;

        auto rdrow = [&](int row, float (&p)[8]) {
            const char* ra = ringc + (size_t)(row & 31) * RB;
            if constexpr (PHF32) {
                // split-half: both reads wave-contiguous (lane*16)
                float4 qa = *(const float4*)(ra + lane * 16);
                float4 qb = *(const float4*)(ra + 1024 + lane * 16);
                p[0] = qa.x; p[1] = qa.y; p[2] = qa.z; p[3] = qa.w;
                p[4] = qb.x; p[5] = qb.y; p[6] = qb.z; p[7] = qb.w;
            } else {
                uint4 q = *((const uint4*)ra + lane);
                unpack8(q, p);
            }
        };
        auto fstep = [&](const float (&p)[8]) {
            float n7 = dpp_shr1_f(a[7], 0.f) * f;
            float n6 = dpp_shr1_f(a[6], 0.f) * f;
            float an0 = (a[0] + n7) * p[0];
            float an1 = __builtin_fmaf(skf[1], n7, a[1] + a[0]) * p[1];
            float an2 = (a[2] + a[1]) * p[2];
            float an3 = __builtin_fmaf(skf[3], a[1], a[3] + a[2]) * p[3];
            float an4 = (a[4] + a[3]) * p[4];
            float an5 = __builtin_fmaf(skf[5], a[3], a[5] + a[4]) * p[5];
            float an6 = (a[6] + a[5]) * p[6];
            float an7 = __builtin_fmaf(skf[7], a[5], a[7] + a[6]) * p[7];
            a[0] = an0; a[1] = an1; a[2] = an2; a[3] = an3;
            a[4] = an4; a[5] = an5; a[6] = an6; a[7] = an7;
        };
        auto rex = [&]() {
            float m = a[0];
#pragma unroll
            for (int s = 1; s < 8; ++s) m = fmaxf(m, a[s]);
            int k = ((__float_as_int(m) >> 23) & 255) - 127;
            int E2 = E + k;
            int En = dpp_shr1_i(E2, E2);
            int Ep = max(E2, En);
            int sc = (E2 - Ep) - k;
#pragma unroll
            for (int s = 0; s < 8; ++s) a[s] = LDEXPF(a[s], sc);
            E = Ep;
            int d = max(En - Ep, -127);
            f = __int_as_float((d + 127) << 23);
        };
        auto issue_row = [&](int r) {
            char* d = ringc + (size_t)(r & 31) * RB;
            const char* s0 = baseP + (size_t)r * RB + lane * 16;
            async16(d, s0);
            if constexpr (PHF32) async16(d + 1024, s0 + 1024);
        };
        auto vwait = [&]() {
            if constexpr (PHF32) asm volatile("s_waitcnt vmcnt(32)" ::: "memory");
            else                 asm volatile("s_waitcnt vmcnt(16)" ::: "memory");
        };

        if (t_idx == T - 1) {
            float pA[8], pB[8];
#pragma unroll
            for (int r = 0; r < 24; ++r) issue_row(r);
            {   // peeled chunk 0
#pragma unroll
                for (int r = 24; r < 32; ++r) issue_row(r);
                vwait();
                __builtin_amdgcn_sched_barrier(0);
                rdrow(0, pA); rdrow(1, pB);
#pragma unroll
                for (int s = 0; s < 8; ++s) {
                    int l = lane * 8 + s;
                    a[s] = (l < 2) ? pA[s] : 0.f;
                }
                E = 0; f = 1.f;
                rdrow(2, pA);
#pragma unroll
                for (int j = 1; j < 8; ++j) {
                    if (j & 1) { fstep(pB); rdrow(j + 2, pB); }
                    else       { fstep(pA); rdrow(j + 2, pA); }
                    if (j == 7) rex();
                }
            }
            for (int k = 1; k < NCH; ++k) {
                if (k + 3 < NCH) {
                    int bs = (k + 3) * 8;
#pragma unroll
                    for (int r = 0; r < 8; ++r) issue_row(bs + r);
                    vwait();
                } else {
                    asm volatile("s_waitcnt vmcnt(0)" ::: "memory");
                }
                __builtin_amdgcn_sched_barrier(0);
#pragma unroll
                for (int j = 0; j < 8; ++j) {
                    int t = k * 8 + j;
                    if (t & 1) { fstep(pB); rdrow(t + 2, pB); }
                    else       { fstep(pA); rdrow(t + 2, pA); }
                    if (j == 7) rex();
                }
            }
#pragma unroll
            for (int s = 0; s < 8; ++s) aph[b * 512 + lane * 8 + s] = a[s];
            aphE[b * 64 + lane] = E;
        } else {
            // fallback: full forward with capture + per-step alignment (rare)
            const int L = 401; int tl = ph_tl[b];
            int l1 = min(2 * tl, L - 1), l2 = max(min(2 * tl - 1, L - 1), 0);
            float capA = 0.f, capB = 0.f; int capEA = 0, capEB = 0;
            for (int t = 0; t < T; ++t) {
                float p[8];
                if constexpr (PHF32) {
                    const float* rp = (const float*)(baseP + (size_t)t * RB);
                    float4 qa = *(const float4*)(rp + lane * 4);
                    float4 qb = *(const float4*)(rp + 256 + lane * 4);
                    p[0] = qa.x; p[1] = qa.y; p[2] = qa.z; p[3] = qa.w;
                    p[4] = qb.x; p[5] = qb.y; p[6] = qb.z; p[7] = qb.w;
                } else {
                    uint4 q = *((const uint4*)(baseP + (size_t)t * RB) + lane);
                    unpack8(q, p);
                }
                if (t == 0) {
#pragma unroll
                    for (int s = 0; s < 8; ++s) {
                        int l = lane * 8 + s;
                        a[s] = (l < 2) ? p[s] : 0.f;
                    }
                    E = 0;
                } else {
                    float n7 = dpp_shr1_f(a[7], 0.f), n6 = dpp_shr1_f(a[6], 0.f);
                    int En = dpp_shr1_i(E, E);
                    int Ep = max(E, En);
                    float o[8];
#pragma unroll
                    for (int s = 0; s < 8; ++s) o[s] = LDEXPF(a[s], E - Ep);
                    float s7 = LDEXPF(n7, En - Ep), s6 = LDEXPF(n6, En - Ep);
                    E = Ep;
#pragma unroll
                    for (int s = 0; s < 8; ++s) {
                        float am1 = (s == 0) ? s7 : o[s - 1];
                        float am2 = (s == 0) ? s6 : ((s == 1) ? s7 : o[s - 2]);
                        a[s] = __builtin_fmaf(skf[s], am2, o[s] + am1) * p[s];
                    }
                }
                if (t == t_idx) {
#pragma unroll
                    for (int s = 0; s < 8; ++s) {
                        int l = lane * 8 + s;
                        if (l == l1) { capA = a[s]; capEA = E; }
                        if (l == l2) { capB = a[s]; capEB = E; }
                    }
                }
                if ((t & 3) == 3) {
                    float m = a[0];
#pragma unroll
                    for (int s = 1; s < 8; ++s) m = fmaxf(m, a[s]);
                    int k = ((__float_as_int(m) >> 23) & 255) - 127;
#pragma unroll
                    for (int s = 0; s < 8; ++s) a[s] = LDEXPF(a[s], -k);
                    E += k;
                }
            }
            finish_loss(capA, capB, capEA, capEB, lane, loss_ph, b);
        }

    } else {
        // ---------------- ph backward ----------------
        const int b = blk - 96;
        const int* tgt = ph_tgt + b * 200;
        const int L = 401; int tl = ph_tl[b];
        int l1 = min(2 * tl, L - 1), l2 = max(min(2 * tl - 1, L - 1), 0);
        float skf[8];
#pragma unroll
        for (int s = 0; s < 8; ++s) {
            int l = lane * 8 + s; float v = 0.f;
            if ((s & 1) && l >= 3 && l <= 400) {
                int i = l >> 1; v = (tgt[i] != tgt[i - 1]) ? 1.f : 0.f;
            }
            skf[s] = v;
        }
        float nskf1 = dpp_shl1_f(skf[1], 0.f);
        float sk1 = skf[3], sk3 = skf[5], sk5 = skf[7], sk7 = nskf1;

        const char* baseP = (const char*)Pph_ + (size_t)b * T * RB;
        const char* srcTop = baseP + (size_t)(T - 1) * RB + lane * 16;
        float g[8];
#pragma unroll
        for (int s = 0; s < 8; ++s) g[s] = 0.f;
        int E = 0; float f = 1.f;

        auto rdrow = [&](int row, float (&p)[8]) {
            const char* ra = ringc + (size_t)(row & 31) * RB;
            if constexpr (PHF32) {
                float4 qa = *(const float4*)(ra + lane * 16);
                float4 qb = *(const float4*)(ra + 1024 + lane * 16);
                p[0] = qa.x; p[1] = qa.y; p[2] = qa.z; p[3] = qa.w;
                p[4] = qb.x; p[5] = qb.y; p[6] = qb.z; p[7] = qb.w;
            } else {
                uint4 q = *((const uint4*)ra + lane);
                unpack8(q, p);
            }
        };
        auto bstep = [&](const float (&p)[8]) {
            float nb0 = dpp_shl1_f(g[0], 0.f) * f;
            float nb1 = dpp_shl1_f(g[1], 0.f) * f;
            float gn0 = (g[0] + g[1]) * p[0];
            float gn1 = __builtin_fmaf(sk1, g[3], g[1] + g[2]) * p[1];
            float gn2 = (g[2] + g[3]) * p[2];
            float gn3 = __builtin_fmaf(sk3, g[5], g[3] + g[4]) * p[3];
            float gn4 = (g[4] + g[5]) * p[4];
            float gn5 = __builtin_fmaf(sk5, g[7], g[5] + g[6]) * p[5];
            float gn6 = (g[6] + g[7]) * p[6];
            float gn7 = __builtin_fmaf(sk7, nb1, g[7] + nb0) * p[7];
            g[0] = gn0; g[1] = gn1; g[2] = gn2; g[3] = gn3;
            g[4] = gn4; g[5] = gn5; g[6] = gn6; g[7] = gn7;
        };
        auto rex = [&]() {
            float m = g[0];
#pragma unroll
            for (int s = 1; s < 8; ++s) m = fmaxf(m, g[s]);
            int k = ((__float_as_int(m) >> 23) & 255) - 127;
            int E2 = E + k;
            int En = dpp_shl1_i(E2, E2);
            int Ep = max(E2, En);
            int sc = (E2 - Ep) - k;
#pragma unroll
            for (int s = 0; s < 8; ++s) g[s] = LDEXPF(g[s], sc);
            E = Ep;
            int d = max(En - Ep, -127);
            f = __int_as_float((d + 127) << 23);
        };
        auto issue_row = [&](int r) {
            char* d = ringc + (size_t)(r & 31) * RB;
            const char* s0 = srcTop - (size_t)r * RB;
            async16(d, s0);
            if constexpr (PHF32) async16(d + 1024, s0 + 1024);
        };
        auto vwait = [&]() {
            if constexpr (PHF32) asm volatile("s_waitcnt vmcnt(32)" ::: "memory");
            else                 asm volatile("s_waitcnt vmcnt(16)" ::: "memory");
        };

        float pA[8], pB[8];
#pragma unroll
        for (int r = 0; r < 24; ++r) issue_row(r);
        {   // peeled chunk 0: init at t=T-1
#pragma unroll
            for (int r = 24; r < 32; ++r) issue_row(r);
            vwait();
            __builtin_amdgcn_sched_barrier(0);
            rdrow(0, pA); rdrow(1, pB);
#pragma unroll
            for (int s = 0; s < 8; ++s) {
                int l = lane * 8 + s;
                g[s] = (l == l1 || l == l2) ? pA[s] : 0.f;
            }
            E = 0; f = 1.f;
            rdrow(2, pA);
#pragma unroll
            for (int j = 1; j < 8; ++j) {
                if (j & 1) { bstep(pB); rdrow(j + 2, pB); }
                else       { bstep(pA); rdrow(j + 2, pA); }
                if (j == 7) rex();
            }
        }
        for (int k = 1; k < NCH; ++k) {
            if (k + 3 < NCH) {
                int bs = (k + 3) * 8;
#pragma unroll
                for (int r = 0; r < 8; ++r) issue_row(bs + r);
                vwait();
            } else {
                asm volatile("s_waitcnt vmcnt(0)" ::: "memory");
            }
            __builtin_amdgcn_sched_barrier(0);
#pragma unroll
            for (int j = 0; j < 8; ++j) {
                int t = k * 8 + j;
                if (t & 1) { bstep(pB); rdrow(t + 2, pB); }
                else       { bstep(pA); rdrow(t + 2, pA); }
                if (j == 7) rex();
            }
        }
#pragma unroll
        for (int s = 0; s < 8; ++s) gph[b * 512 + lane * 8 + s] = g[s];
        gphE[b * 64 + lane] = E;
    }
}

// ===========================================================================
// combine: p = sum_l alpha_tm[l] * (g[l] + g[l+1] + allow[l+2]*g[l+2])
// (verbatim round-11, passing)
// ===========================================================================
__global__ __launch_bounds__(64) void combine_kernel(
    const int* __restrict__ err_tgt, const int* __restrict__ ph_tgt,
    const int* __restrict__ err_il, const int* __restrict__ ph_il,
    const float* __restrict__ aerr, const int* __restrict__ aerrE,
    const float* __restrict__ gerr, const int* __restrict__ gerrE,
    const float* __restrict__ aph, const int* __restrict__ aphE,
    const float* __restrict__ gph, const int* __restrict__ gphE,
    float* __restrict__ loss_err, float* __restrict__ loss_ph, int T) {
    const int blk = blockIdx.x;
    const int lane = threadIdx.x & 63;
    if (blk < 32) {
        const int b = blk;
        int t_idx = min(max(err_il[b] - 1, 0), T - 1);
        if (t_idx != T - 1) return;
        const int* tgt = err_tgt + b * 50;
        float skip1f;
        {
            int l = lane * 2 + 1; bool sk = false;
            if (l >= 3 && l <= 100) { int i = l >> 1; sk = (tgt[i] != tgt[i - 1]); }
            skip1f = sk ? 1.f : 0.f;
        }
        float a0 = aerr[b * 128 + lane * 2], a1 = aerr[b * 128 + lane * 2 + 1];
        int Ea = aerrE[b * 64 + lane];
        float g0 = gerr[b * 128 + lane * 2], g1 = gerr[b * 128 + lane * 2 + 1];
        int Eb = gerrE[b * 64 + lane];
        float nb0 = __shfl_down(g0, 1), nb1 = __shfl_down(g1, 1);
        int Ebn = __shfl_down(Eb, 1);
        float skp2 = __shfl_down(skip1f, 1);
        if (lane == 63) { nb0 = 0.f; nb1 = 0.f; Ebn = Eb; skp2 = 0.f; }
        int Em = max(Eb, Ebn);
        float o0 = LDEXPF(g0, Eb - Em), o1 = LDEXPF(g1, Eb - Em);
        float t0 = LDEXPF(nb0, Ebn - Em), t1 = LDEXPF(nb1, Ebn - Em);
        float bc0 = o0 + o1;
        float bc1 = __builtin_fmaf(skp2, t1, o1 + t0);
        float dot = __builtin_fmaf(a0, bc0, a1 * bc1);
        float v = (dot > 0.f) ? (float)(Ea + Em) + LOG2F(dot) : NEG2;
        float mm = v;
#pragma unroll
        for (int i = 1; i < 64; i <<= 1) mm = fmaxf(mm, __shfl_xor(mm, i));
        float sum = EXP2F(v - mm);
#pragma unroll
        for (int i = 1; i < 64; i <<= 1) sum += __shfl_xor(sum, i);
        if (lane == 0) loss_err[b] = -(mm + LOG2F(sum)) * LN2;
    } else {
        const int b = blk - 32;
        int t_idx = min(max(ph_il[b] - 1, 0), T - 1);
        if (t_idx != T - 1) return;
        const int* tgt = ph_tgt + b * 200;
        float skf[8];
#pragma unroll
        for (int s = 0; s < 8; ++s) {
            int l = lane * 8 + s; float v = 0.f;
            if ((s & 1) && l >= 3 && l <= 400) {
                int i = l >> 1; v = (tgt[i] != tgt[i - 1]) ? 1.f : 0.f;
            }
            skf[s] = v;
        }
        float a[8], g[8];
#pragma unroll
        for (int s = 0; s < 8; ++s) {
            a[s] = aph[b * 512 + lane * 8 + s];
            g[s] = gph[b * 512 + lane * 8 + s];
        }
        int Ea = aphE[b * 64 + lane];
        int Eb = gphE[b * 64 + lane];
        float nb0 = __shfl_down(g[0], 1), nb1 = __shfl_down(g[1], 1);
        int Ebn = __shfl_down(Eb, 1);
        float nskf1 = __shfl_down(skf[1], 1);
        if (lane == 63) { nb0 = 0.f; nb1 = 0.f; Ebn = Eb; nskf1 = 0.f; }
        float skp2[8];
        skp2[0] = 0.f; skp2[1] = skf[3]; skp2[2] = 0.f; skp2[3] = skf[5];
        skp2[4] = 0.f; skp2[5] = skf[7]; skp2[6] = 0.f; skp2[7] = nskf1;
        int Em = max(Eb, Ebn);
        float o[8];
#pragma unroll
        for (int s = 0; s < 8; ++s) o[s] = LDEXPF(g[s], Eb - Em);
        float t0 = LDEXPF(nb0, Ebn - Em), t1 = LDEXPF(nb1, Ebn - Em);
        float dot = 0.f;
#pragma unroll
        for (int s = 0; s < 8; ++s) {
            float bp1 = (s < 7) ? o[s + 1] : t0;
            float bp2 = (s < 6) ? o[s + 2] : ((s == 6) ? t0 : t1);
            float bc = __builtin_fmaf(skp2[s], bp2, o[s] + bp1);
            dot = __builtin_fmaf(a[s], bc, dot);
        }
        float v = (dot > 0.f) ? (float)(Ea + Em) + LOG2F(dot) : NEG2;
        float mm = v;
#pragma unroll
        for (int i = 1; i < 64; i <<= 1) mm = fmaxf(mm, __shfl_xor(mm, i));
        float sum = EXP2F(v - mm);
#pragma unroll
        for (int i = 1; i < 64; i <<= 1) sum += __shfl_xor(sum, i);
        if (lane == 0) loss_ph[b] = -(mm + LOG2F(sum)) * LN2;
    }
}

// ---------------------------------------------------------------------------
// Final: focal transform + means + total. One wave.
// ---------------------------------------------------------------------------
__global__ void final_kernel(const float* __restrict__ loss_err,
                             const float* __restrict__ loss_ph,
                             float* __restrict__ out) {
    int lane = threadIdx.x & 63;
    float fe = 0.f, fp = 0.f;
    if (lane < 32) {
        float l = fmaxf(loss_err[lane], 1e-6f);
        float pt = fminf(fmaxf(EXP2F(-l * LOG2E), 1e-6f), 1.0f);
        float om = 1.f - pt;
        fe = om * om * l;
        l = fmaxf(loss_ph[lane], 1e-6f);
        pt = fminf(fmaxf(EXP2F(-l * LOG2E), 1e-6f), 1.0f);
        om = 1.f - pt;
        fp = om * om * l;
    }
#pragma unroll
    for (int i = 1; i < 64; i <<= 1) {
        fe += __shfl_xor(fe, i);
        fp += __shfl_xor(fp, i);
    }
    if (lane == 0) {
        float err = fe / 32.f;
        float ph = fp / 32.f;
        out[0] = err + ph;
        out[1] = err;
        out[2] = ph;
    }
}

// ---------------------------------------------------------------------------
extern "C" void kernel_launch(void* const* d_in, const int* in_sizes, int n_in,
                              void* d_out, int out_size, void* d_ws, size_t ws_size,
                              hipStream_t stream) {
    const int B = 32, T = 2000;
    const float* err_logits = (const float*)d_in[0];  // [32,2000,8]
    const float* ph_logits  = (const float*)d_in[1];  // [32,2000,128]
    const int* err_tgt = (const int*)d_in[2];         // [32,50]
    const int* ph_tgt  = (const int*)d_in[3];         // [32,200]
    const int* err_il  = (const int*)d_in[4];
    const int* ph_il   = (const int*)d_in[5];
    const int* err_tl  = (const int*)d_in[6];
    const int* ph_tl   = (const int*)d_in[7];
    float* out = (float*)d_out;

    const size_t PH_F32_B  = (size_t)B * T * 512 * 4;   // 131.1 MB
    const size_t PH_BF16_B = (size_t)B * T * 512 * 2;   //  65.5 MB
    const size_t ERR_B     = (size_t)B * T * 128 * 2;   //  16.4 MB
    const size_t STATE_B   = ((size_t)B * 512 * 4) * 2 + ((size_t)B * 64 * 4) * 4 +
                             ((size_t)B * 128 * 4) * 2 + (size_t)B * 4 * 2 + 1024;

    const bool f32ok = ws_size >= PH_F32_B + ERR_B + STATE_B;
    const size_t phB = f32ok ? PH_F32_B : PH_BF16_B;

    char* p = (char*)d_ws;
    void* Pph = (void*)p;                 p += phB;
    unsigned short* Perr = (unsigned short*)p; p += ERR_B;
    float* aph  = (float*)p; p += (size_t)B * 512 * 4;
    int*   aphE = (int*)p;   p += (size_t)B * 64 * 4;
    float* gph  = (float*)p; p += (size_t)B * 512 * 4;
    int*   gphE = (int*)p;   p += (size_t)B * 64 * 4;
    float* aerr = (float*)p; p += (size_t)B * 128 * 4;
    int*   aerrE= (int*)p;   p += (size_t)B * 64 * 4;
    float* gerr = (float*)p; p += (size_t)B * 128 * 4;
    int*   gerrE= (int*)p;   p += (size_t)B * 64 * 4;
    float* loss_err = (float*)p; p += B * 4;
    float* loss_ph  = (float*)p; p += B * 4;

    if (f32ok) {
        prob_kernel<true><<<32000, 256, 0, stream>>>(ph_logits, ph_tgt, Pph,
                                                     err_logits, err_tgt, Perr);
        ctc9_kernel<true><<<128, 64, 0, stream>>>(Perr, Pph, err_tgt, ph_tgt,
                                                  err_il, ph_il, err_tl, ph_tl,
                                                  aerr, aerrE, gerr, gerrE,
                                                  aph, aphE, gph, gphE,
                                                  loss_err, loss_ph, T);
    } else {
        prob_kernel<false><<<32000, 256, 0, stream>>>(ph_logits, ph_tgt, Pph,
                                                      err_logits, err_tgt, Perr);
        ctc9_kernel<false><<<128, 64, 0, stream>>>(Perr, Pph, err_tgt, ph_tgt,
                                                   err_il, ph_il, err_tl, ph_tl,
                                                   aerr, aerrE, gerr, gerrE,
                                                   aph, aphE, gph, gphE,
                                                   loss_err, loss_ph, T);
    }
    combine_kernel<<<64, 64, 0, stream>>>(err_tgt, ph_tgt, err_il, ph_il,
                                          aerr, aerrE, gerr, gerrE,
                                          aph, aphE, gph, gphE,
                                          loss_err, loss_ph, T);
    final_kernel<<<1, 64, 0, stream>>>(loss_err, loss_ph, out);
}